// Round 13
// baseline (1477.354 us; speedup 1.0000x reference)
//
#include <hip/hip_runtime.h>
#include <hip/hip_bf16.h>

typedef unsigned short u16;
typedef unsigned int   u32;
typedef unsigned char  u8;
typedef __attribute__((ext_vector_type(8)))  __bf16 bf16x8;
typedef __attribute__((ext_vector_type(8)))  u16    u16x8;
typedef __attribute__((ext_vector_type(16))) float  f32x16;
typedef __attribute__((ext_vector_type(4)))  int    i32x4;
typedef __attribute__((ext_vector_type(8)))  int    i32x8;

#define DT     0.1f
#define NUNF   6
#define WSCALE 256.0f       // Wh packed as fp8(W*256); z_true = acc/256
#define SCALE1 0x7F7F7F7F   // E8M0 127 = 2^0 in all 4 bytes (scale = 1.0)

template<int N> struct ic { static constexpr int value = N; };

__device__ __forceinline__ u16 f2bf(float f) {
    __hip_bfloat16 h = __float2bfloat16(f);   // RNE
    return __builtin_bit_cast(u16, h);
}
__device__ __forceinline__ float bf2f(u16 u) {
    return __uint_as_float(((u32)u) << 16);
}
__device__ __forceinline__ u32 pk2(float a, float b) {
    return (u32)f2bf(a) | ((u32)f2bf(b) << 16);
}
// pack 4 floats -> 4 fp8 e4m3 bytes (OCP on gfx950)
__device__ __forceinline__ u32 pkfp8x4(float a, float b, float c, float d) {
    u32 v = __builtin_amdgcn_cvt_pk_fp8_f32(a, b, 0, false);
    v     = __builtin_amdgcn_cvt_pk_fp8_f32(c, d, v, true);
    return v;
}

// ---------------------------------------------------------------------------
// Pack W (fp32 [1024][1536]):
//  Wxp  (bf16, 1 MB, 32x32x16 frag layout):
//    [ks<32][nb<32][lane<64][i<8] = W[nb*32+(l&31)][ks*16+(l>>5)*8+i]
//  Whp8 (fp8*256, 1 MB, 32x32x64 MX frag layout, 32 B/lane):
//    [ks16<16][nb<32][lane<64][i<32] = W[nb*32+(l&31)][512 + ks16*64+(l>>5)*32+i]
// ---------------------------------------------------------------------------
__global__ void pack_w(const float* __restrict__ W,
                       u16* __restrict__ Wxp, u8* __restrict__ Whp8)
{
    int t = blockIdx.x * 256 + threadIdx.x;
    if (t < 65536) {
        int lane = t & 63;
        int nb   = (t >> 6) & 31;
        int ks   = t >> 11;            // 0..31
        const float* src = W + (size_t)(nb*32 + (lane&31))*1536 + ks*16 + ((lane>>5)<<3);
        u16* dst = Wxp + ((size_t)(ks*32 + nb)*64 + lane)*8;
        float4 v0 = *(const float4*)(src);
        float4 v1 = *(const float4*)(src + 4);
        *(ushort4*)(dst)     = make_ushort4(f2bf(v0.x), f2bf(v0.y), f2bf(v0.z), f2bf(v0.w));
        *(ushort4*)(dst + 4) = make_ushort4(f2bf(v1.x), f2bf(v1.y), f2bf(v1.z), f2bf(v1.w));
    } else {
        int t2   = t - 65536;          // 0..131071, 8 bytes each
        int ig   = t2 & 3;
        int lane = (t2 >> 2) & 63;
        int nb   = (t2 >> 8) & 31;
        int ks   = t2 >> 13;           // 0..15
        const float* src = W + (size_t)(nb*32 + (lane&31))*1536 + 512
                         + ks*64 + ((lane>>5)<<5) + (ig<<3);
        u8* dst = Whp8 + (((size_t)(ks*32 + nb)*64 + lane)<<5) + (ig<<3);
        float4 v0 = *(const float4*)(src);
        float4 v1 = *(const float4*)(src + 4);
        u32 lo = pkfp8x4(v0.x*WSCALE, v0.y*WSCALE, v0.z*WSCALE, v0.w*WSCALE);
        u32 hi = pkfp8x4(v1.x*WSCALE, v1.y*WSCALE, v1.z*WSCALE, v1.w*WSCALE);
        *(uint2*)dst = make_uint2(lo, hi);
    }
}

// ---------------------------------------------------------------------------
// bf16 gemm (xp prologue): acc[2] += Wp (A, frag-linear L2) @ arg (B, LDS).
// ---------------------------------------------------------------------------
template<int KS>
__device__ __forceinline__ void gemm2(f32x16 (&acc)[2], const u16* Bl,
                                      const u16* __restrict__ Ap,
                                      int lane, int wn)
{
    const bf16x8* B8 = (const bf16x8*)Bl;
    const bf16x8* A8 = (const bf16x8*)Ap;
    const int ab = ((wn << 1) << 6) + lane;
#pragma unroll 2
    for (int ks = 0; ks < KS; ks++) {
        bf16x8 b  = B8[ks*64 + lane];
        bf16x8 a0 = A8[ab + ks*2048];
        bf16x8 a1 = A8[ab + ks*2048 + 64];
        acc[0] = __builtin_amdgcn_mfma_f32_32x32x16_bf16(a0, b, acc[0], 0, 0, 0);
        acc[1] = __builtin_amdgcn_mfma_f32_32x32x16_bf16(a1, b, acc[1], 0, 0, 0);
    }
}

// ---------------------------------------------------------------------------
// MX fp8 gemm (main loop, one 32x32 fragment): acc += Whp8-panel jb (A, L2)
// @ arg8 (B, LDS) via mfma_scale_f32_32x32x64_f8f6f4, unity E8M0 scales.
// Per ks: 2 ds_read_b128 + 2 global 16B + 1 MFMA.
// ---------------------------------------------------------------------------
__device__ __forceinline__ void gemm_mx(f32x16& acc, const u8* Bl,
                                        const u8* __restrict__ Ap,
                                        int lane, int jb)
{
    const i32x4* B4 = (const i32x4*)Bl;           // 16-B granules
    const i32x4* A4 = (const i32x4*)Ap;
    const int ab = (jb*64 + lane)*2;              // + ks*4096
    const int bb = lane;                          // + ks*128 (+64 for half 1)
#pragma unroll 2
    for (int ks = 0; ks < 16; ks++) {
        i32x4 b0 = B4[ks*128 + bb];
        i32x4 b1 = B4[ks*128 + 64 + bb];
        i32x4 a0 = A4[ab + ks*4096];
        i32x4 a1 = A4[ab + ks*4096 + 1];
        i32x8 a = {a0[0],a0[1],a0[2],a0[3],a1[0],a1[1],a1[2],a1[3]};
        i32x8 b = {b0[0],b0[1],b0[2],b0[3],b1[0],b1[1],b1[2],b1[3]};
        acc = __builtin_amdgcn_mfma_scale_f32_32x32x64_f8f6f4(
                  a, b, acc, 0, 0, 0, SCALE1, 0, SCALE1);
    }
}

// ---------------------------------------------------------------------------
// Fused kernel: block = 32 batch rows x H=1024, 1024 thr = 16 waves (16 wn).
// Round 9 numerics exactly; NEW: phase-shifted wave schedule. Each stage is
// two sub-ops per half: G(F) = {xp-load, gemm into acc[F]} (L2-stream) and
// T(F) = {tanh/hacc, writeArg} (VALU). EVEN waves run G0 T0 G1 T1; ODD waves
// run G1 G0 T1 T0. While even waves are in a VALU tail, odd waves are
// streaming L2 (and vice versa) -> the two pipes overlap across wave groups.
// Zero register delta: both acc halves already persist in AGPRs; per-thread
// FP order is unchanged -> bit-identical output to round 9.
// LDS: ARG8 dbuf 2x32 KB + XPl 64 KB = 128 KB (1 block/CU, 16 waves).
// ---------------------------------------------------------------------------
__global__ __launch_bounds__(1024, 4)
void fused_rk4(const float* __restrict__ X,     // [32768][512]
               const float* __restrict__ S,     // [32768][1024]
               const float* __restrict__ Bb,    // [1024]
               const u16*  __restrict__ Wxp,
               const u8*   __restrict__ Whp8,
               float* __restrict__ Out)         // [32768][1024]
{
    __shared__ __align__(16) u8  ARGA[32768];   // 32 KB fp8 h-arg frags (buf 0)
    __shared__ __align__(16) u8  ARGB[32768];   // 32 KB fp8 h-arg frags (buf 1)
    __shared__ __align__(16) u16 XPl[32768];    // 64 KB: X-frags, then xp*256

    const int tid  = threadIdx.x;
    const int lane = tid & 63;
    const int wn   = tid >> 6;      // 0..15
    const int r    = lane & 31;
    const int hi   = lane >> 5;
    const int r0   = blockIdx.x << 5;

    // ---- stage X (bf16 B-frags, 32 KB) into XPl[0..16384) ----
#pragma unroll
    for (int g2 = 0; g2 < 2; g2++) {
        const int g  = tid + (g2 << 10);        // 0..2047
        const int ks = g >> 6, ln = g & 63;
        const float* src = X + (size_t)(r0 + (ln & 31))*512 + ks*16 + ((ln>>5)<<3);
        float4 v0 = *(const float4*)src;
        float4 v1 = *(const float4*)(src + 4);
        u16x8 pv = { f2bf(v0.x), f2bf(v0.y), f2bf(v0.z), f2bf(v0.w),
                     f2bf(v1.x), f2bf(v1.y), f2bf(v1.z), f2bf(v1.w) };
        *(u16x8*)(XPl + ks*512 + ln*8) = pv;
    }

    // ---- h init + bias into acc ----
    float h[2][16];
    f32x16 acc[2];
#pragma unroll
    for (int f = 0; f < 2; f++) {
        const int jb = (wn << 1) + f;
#pragma unroll
        for (int q = 0; q < 4; q++) {
            const int j0 = (jb << 5) + (q << 3) + (hi << 2);
            float4 hv = *(const float4*)(S + (size_t)(r0 + r)*1024 + j0);
            float4 bb = *(const float4*)(Bb + j0);
            h[f][4*q+0] = hv.x; h[f][4*q+1] = hv.y;
            h[f][4*q+2] = hv.z; h[f][4*q+3] = hv.w;
            acc[f][4*q+0] = bb.x; acc[f][4*q+1] = bb.y;
            acc[f][4*q+2] = bb.z; acc[f][4*q+3] = bb.w;
        }
    }

    __syncthreads();                 // X-frags visible

    // ---- xp^T = Wx @ X^T + b (bf16) ----
    gemm2<32>(acc, XPl, Wxp, lane, wn);

    __syncthreads();                 // all waves done reading X region

    // ---- xp*256 -> XPl (bf16 frag layout, overwrites X region) ----
#pragma unroll
    for (int f = 0; f < 2; f++)
#pragma unroll
        for (int q = 0; q < 4; q++) {
            const int idx = ((((wn << 3) + (f << 2) + q) << 6) + lane) << 2;
            *(uint2*)&XPl[idx] =
                make_uint2(pk2(acc[f][4*q+0]*WSCALE, acc[f][4*q+1]*WSCALE),
                           pk2(acc[f][4*q+2]*WSCALE, acc[f][4*q+3]*WSCALE));
        }

    float hacc[2][16];

    // ---- per-half arg write (fp8, MX B-frag layout; addresses = round 9) ----
    auto writeHalf = [&](u8* wb, auto FC, bool useK, float cs) {
        constexpr int F = decltype(FC)::value;
        const int jb = (wn << 1) + F;
        const int base = ((jb >> 1) << 11) + ((((jb & 1) << 5) + r) << 4) + (hi << 2);
#pragma unroll
        for (int q = 0; q < 4; q++) {
            float v0 = h[F][4*q+0], v1 = h[F][4*q+1];
            float v2 = h[F][4*q+2], v3 = h[F][4*q+3];
            if (useK) {
                v0 += cs * acc[F][4*q+0]; v1 += cs * acc[F][4*q+1];
                v2 += cs * acc[F][4*q+2]; v3 += cs * acc[F][4*q+3];
            }
            const int idx = base + ((q >> 1) << 10) + ((q & 1) << 3);
            *(u32*)(wb + idx) = pkfp8x4(v0, v1, v2, v3);
        }
    };

    // ---- G(F): acc[F] := 256*xp, then gemm (the L2-stream sub-op) ----
    auto gemmHalf = [&](auto FC, const u8* rb) {
        constexpr int F = decltype(FC)::value;
#pragma unroll
        for (int q = 0; q < 4; q++) {
            const int idx = ((((wn << 3) + (F << 2) + q) << 6) + lane) << 2;
            uint2 xv = *(const uint2*)&XPl[idx];
            acc[F][4*q+0] = bf2f((u16)xv.x);
            acc[F][4*q+1] = __uint_as_float(xv.x & 0xffff0000u);
            acc[F][4*q+2] = bf2f((u16)xv.y);
            acc[F][4*q+3] = __uint_as_float(xv.y & 0xffff0000u);
        }
        gemm_mx(acc[F], rb, Whp8, lane, (wn << 1) + F);
    };

    // ---- T(F): tanh/hacc + writeArg (the VALU sub-op) ----
    auto tailHalf = [&](auto FC, u8* wb, int s, int u, float wk) {
        constexpr int F = decltype(FC)::value;
#pragma unroll
        for (int e = 0; e < 16; e++) {
            const float ee = __expf((2.0f / WSCALE) * acc[F][e]);
            const float k  = fmaf(-2.0f * DT, __frcp_rn(ee + 1.0f), DT);
            hacc[F][e] = fmaf(wk, k, hacc[F][e]);
            acc[F][e]  = k;
        }
        if (s < 3) {
            writeHalf(wb, FC, true, (s < 2) ? 0.5f : 1.0f);   // arg := h + cs*k
        } else {
#pragma unroll
            for (int e = 0; e < 16; e++) h[F][e] = hacc[F][e]; // h := hacc
            if (u < NUNF - 1) writeHalf(wb, FC, false, 0.0f);  // arg := h
        }
    };

    writeHalf(ARGA, ic<0>{}, false, 0.0f);   // arg := h  (buffer 0)
    writeHalf(ARGA, ic<1>{}, false, 0.0f);
    __syncthreads();

#pragma unroll 1
    for (int u = 0; u < NUNF; u++) {
        // hacc := h (base for this unfold's weighted k-sum)
#pragma unroll
        for (int f = 0; f < 2; f++)
#pragma unroll
            for (int e = 0; e < 16; e++) hacc[f][e] = h[f][e];

#pragma unroll 1
        for (int s = 0; s < 4; s++) {
            const int   t4 = (u << 2) + s;           // global stage index
            const u8*   rb = (t4 & 1) ? ARGB : ARGA;
            u8*         wb = (t4 & 1) ? ARGA : ARGB;
            const float wk = (s == 1 || s == 2) ? (1.0f / 3.0f) : (1.0f / 6.0f);

            if (wn & 1) {
                // odd waves: G1 G0 T1 T0  (stream first, tail later)
                gemmHalf(ic<1>{}, rb);
                gemmHalf(ic<0>{}, rb);
                tailHalf(ic<1>{}, wb, s, u, wk);
                tailHalf(ic<0>{}, wb, s, u, wk);
            } else {
                // even waves: G0 T0 G1 T1  (tail early, stream later)
                gemmHalf(ic<0>{}, rb);
                tailHalf(ic<0>{}, wb, s, u, wk);
                gemmHalf(ic<1>{}, rb);
                tailHalf(ic<1>{}, wb, s, u, wk);
            }

            if (s < 3 || u < NUNF - 1) __syncthreads();
        }
    }

    // ---- output: float4 per (f,q) ----
#pragma unroll
    for (int f = 0; f < 2; f++) {
        const int jb = (wn << 1) + f;
#pragma unroll
        for (int q = 0; q < 4; q++) {
            const int j0 = (jb << 5) + (q << 3) + (hi << 2);
            float4 ov = make_float4(h[f][4*q+0], h[f][4*q+1],
                                    h[f][4*q+2], h[f][4*q+3]);
            *(float4*)(Out + (size_t)(r0 + r)*1024 + j0) = ov;
        }
    }
}

// ---------------------------------------------------------------------------
extern "C" void kernel_launch(void* const* d_in, const int* in_sizes, int n_in,
                              void* d_out, int out_size, void* d_ws, size_t ws_size,
                              hipStream_t stream)
{
    const float* X  = (const float*)d_in[0];   // 32768*512
    const float* S  = (const float*)d_in[1];   // 32768*1024
    const float* W  = (const float*)d_in[2];   // 1024*1536
    const float* Bb = (const float*)d_in[3];   // 1024
    float* Out = (float*)d_out;

    u16* Wxp  = (u16*)d_ws;                    // 1 MB bf16 frags (Wx)
    u8*  Whp8 = (u8*)d_ws + (1 << 20);         // 1 MB fp8 MX frags (Wh*256)

    pack_w<<<768, 256, 0, stream>>>(W, Wxp, Whp8);
    fused_rk4<<<1024, 1024, 0, stream>>>(X, S, Bb, Wxp, Whp8, Out);
}

// Round 14
// 1357.239 us; speedup vs baseline: 1.0885x; 1.0885x over previous
//
#include <hip/hip_runtime.h>
#include <hip/hip_bf16.h>

typedef unsigned short u16;
typedef unsigned int   u32;
typedef unsigned char  u8;
typedef __attribute__((ext_vector_type(8)))  __bf16 bf16x8;
typedef __attribute__((ext_vector_type(8)))  u16    u16x8;
typedef __attribute__((ext_vector_type(16))) float  f32x16;
typedef __attribute__((ext_vector_type(4)))  int    i32x4;
typedef __attribute__((ext_vector_type(8)))  int    i32x8;

#define DT     0.1f
#define NUNF   6
#define WSCALE 256.0f       // Wh packed as fp8(W*256); z_true = acc/256
#define SCALE1 0x7F7F7F7F   // E8M0 127 = 2^0 in all 4 bytes (scale = 1.0)

__device__ __forceinline__ u16 f2bf(float f) {
    __hip_bfloat16 h = __float2bfloat16(f);   // RNE
    return __builtin_bit_cast(u16, h);
}
__device__ __forceinline__ float bf2f(u16 u) {
    return __uint_as_float(((u32)u) << 16);
}
__device__ __forceinline__ u32 pk2(float a, float b) {
    return (u32)f2bf(a) | ((u32)f2bf(b) << 16);
}
// pack 4 floats -> 4 fp8 e4m3 bytes (OCP on gfx950)
__device__ __forceinline__ u32 pkfp8x4(float a, float b, float c, float d) {
    u32 v = __builtin_amdgcn_cvt_pk_fp8_f32(a, b, 0, false);
    v     = __builtin_amdgcn_cvt_pk_fp8_f32(c, d, v, true);
    return v;
}

// ---------------------------------------------------------------------------
// Pack W (fp32 [1024][1536]):
//  Wxp  (bf16, 1 MB, 32x32x16 frag layout):
//    [ks<32][nb<32][lane<64][i<8] = W[nb*32+(l&31)][ks*16+(l>>5)*8+i]
//  Whp8 (fp8*256, 1 MB, 32x32x64 MX frag layout, 32 B/lane):
//    [ks16<16][nb<32][lane<64][i<32] = W[nb*32+(l&31)][512 + ks16*64+(l>>5)*32+i]
// ---------------------------------------------------------------------------
__global__ void pack_w(const float* __restrict__ W,
                       u16* __restrict__ Wxp, u8* __restrict__ Whp8)
{
    int t = blockIdx.x * 256 + threadIdx.x;
    if (t < 65536) {
        int lane = t & 63;
        int nb   = (t >> 6) & 31;
        int ks   = t >> 11;            // 0..31
        const float* src = W + (size_t)(nb*32 + (lane&31))*1536 + ks*16 + ((lane>>5)<<3);
        u16* dst = Wxp + ((size_t)(ks*32 + nb)*64 + lane)*8;
        float4 v0 = *(const float4*)(src);
        float4 v1 = *(const float4*)(src + 4);
        *(ushort4*)(dst)     = make_ushort4(f2bf(v0.x), f2bf(v0.y), f2bf(v0.z), f2bf(v0.w));
        *(ushort4*)(dst + 4) = make_ushort4(f2bf(v1.x), f2bf(v1.y), f2bf(v1.z), f2bf(v1.w));
    } else {
        int t2   = t - 65536;          // 0..131071, 8 bytes each
        int ig   = t2 & 3;
        int lane = (t2 >> 2) & 63;
        int nb   = (t2 >> 8) & 31;
        int ks   = t2 >> 13;           // 0..15
        const float* src = W + (size_t)(nb*32 + (lane&31))*1536 + 512
                         + ks*64 + ((lane>>5)<<5) + (ig<<3);
        u8* dst = Whp8 + (((size_t)(ks*32 + nb)*64 + lane)<<5) + (ig<<3);
        float4 v0 = *(const float4*)(src);
        float4 v1 = *(const float4*)(src + 4);
        u32 lo = pkfp8x4(v0.x*WSCALE, v0.y*WSCALE, v0.z*WSCALE, v0.w*WSCALE);
        u32 hi = pkfp8x4(v1.x*WSCALE, v1.y*WSCALE, v1.z*WSCALE, v1.w*WSCALE);
        *(uint2*)dst = make_uint2(lo, hi);
    }
}

// ---------------------------------------------------------------------------
// bf16 gemm (xp prologue): acc[2] += Wp (A, frag-linear L2) @ arg (B, LDS).
// ---------------------------------------------------------------------------
template<int KS>
__device__ __forceinline__ void gemm2(f32x16 (&acc)[2], const u16* Bl,
                                      const u16* __restrict__ Ap,
                                      int lane, int wn)
{
    const bf16x8* B8 = (const bf16x8*)Bl;
    const bf16x8* A8 = (const bf16x8*)Ap;
    const int ab = ((wn << 1) << 6) + lane;
#pragma unroll 2
    for (int ks = 0; ks < KS; ks++) {
        bf16x8 b  = B8[ks*64 + lane];
        bf16x8 a0 = A8[ab + ks*2048];
        bf16x8 a1 = A8[ab + ks*2048 + 64];
        acc[0] = __builtin_amdgcn_mfma_f32_32x32x16_bf16(a0, b, acc[0], 0, 0, 0);
        acc[1] = __builtin_amdgcn_mfma_f32_32x32x16_bf16(a1, b, acc[1], 0, 0, 0);
    }
}

// ---------------------------------------------------------------------------
// MX fp8 gemm, BOTH fragments fused: acc[0,1] += Whp8 panels (2wn, 2wn+1)
// @ arg8 (B, LDS). KEY: B does not depend on the fragment -> load b0,b1 ONCE
// and feed 2 MFMAs, halving LDS traffic vs two separate gemm calls.
// Per ks: 2 ds_read_b128 + 4 global 16B + 2 MFMA. unroll 4 deepens the
// in-flight load window (latency-bound L2 stream).
// ---------------------------------------------------------------------------
__device__ __forceinline__ void gemm_mx2(f32x16 (&acc)[2], const u8* Bl,
                                         const u8* __restrict__ Ap,
                                         int lane, int wn)
{
    const i32x4* B4 = (const i32x4*)Bl;           // 16-B granules (LDS)
    const i32x4* A4 = (const i32x4*)Ap;           // 16-B granules (L2)
    const int ab = (((wn << 1) << 6) + lane) << 1;   // frag0 base; frag1 at +128
#pragma unroll 4
    for (int ks = 0; ks < 16; ks++) {
        i32x4 b0  = B4[ks*128 + lane];
        i32x4 b1  = B4[ks*128 + 64 + lane];
        i32x4 a00 = A4[ab + ks*4096];
        i32x4 a01 = A4[ab + ks*4096 + 1];
        i32x4 a10 = A4[ab + ks*4096 + 128];
        i32x4 a11 = A4[ab + ks*4096 + 129];
        i32x8 b  = {b0[0],b0[1],b0[2],b0[3],b1[0],b1[1],b1[2],b1[3]};
        i32x8 A0 = {a00[0],a00[1],a00[2],a00[3],a01[0],a01[1],a01[2],a01[3]};
        i32x8 A1 = {a10[0],a10[1],a10[2],a10[3],a11[0],a11[1],a11[2],a11[3]};
        acc[0] = __builtin_amdgcn_mfma_scale_f32_32x32x64_f8f6f4(
                     A0, b, acc[0], 0, 0, 0, SCALE1, 0, SCALE1);
        acc[1] = __builtin_amdgcn_mfma_scale_f32_32x32x64_f8f6f4(
                     A1, b, acc[1], 0, 0, 0, SCALE1, 0, SCALE1);
    }
}

// ---------------------------------------------------------------------------
// Fused kernel: block = 32 batch rows x H=1024, 1024 thr = 16 waves (16 wn).
// Round 9 structure and numerics exactly (fp32 hacc, dbuf ARG8, one barrier
// per stage); ONLY change: the two per-fragment gemms are fused so the shared
// B operand is read from LDS once (1 MB -> 0.5 MB LDS traffic per stage).
// LDS: ARG8 dbuf 2x32 KB + XPl 64 KB = 128 KB (1 block/CU, 16 waves).
// ---------------------------------------------------------------------------
__global__ __launch_bounds__(1024, 4)
void fused_rk4(const float* __restrict__ X,     // [32768][512]
               const float* __restrict__ S,     // [32768][1024]
               const float* __restrict__ Bb,    // [1024]
               const u16*  __restrict__ Wxp,
               const u8*   __restrict__ Whp8,
               float* __restrict__ Out)         // [32768][1024]
{
    __shared__ __align__(16) u8  ARGA[32768];   // 32 KB fp8 h-arg frags (buf 0)
    __shared__ __align__(16) u8  ARGB[32768];   // 32 KB fp8 h-arg frags (buf 1)
    __shared__ __align__(16) u16 XPl[32768];    // 64 KB: X-frags, then xp*256

    const int tid  = threadIdx.x;
    const int lane = tid & 63;
    const int wn   = tid >> 6;      // 0..15
    const int r    = lane & 31;
    const int hi   = lane >> 5;
    const int r0   = blockIdx.x << 5;

    // ---- stage X (bf16 B-frags, 32 KB) into XPl[0..16384) ----
#pragma unroll
    for (int g2 = 0; g2 < 2; g2++) {
        const int g  = tid + (g2 << 10);        // 0..2047
        const int ks = g >> 6, ln = g & 63;
        const float* src = X + (size_t)(r0 + (ln & 31))*512 + ks*16 + ((ln>>5)<<3);
        float4 v0 = *(const float4*)src;
        float4 v1 = *(const float4*)(src + 4);
        u16x8 pv = { f2bf(v0.x), f2bf(v0.y), f2bf(v0.z), f2bf(v0.w),
                     f2bf(v1.x), f2bf(v1.y), f2bf(v1.z), f2bf(v1.w) };
        *(u16x8*)(XPl + ks*512 + ln*8) = pv;
    }

    // ---- h init + bias into acc ----
    float h[2][16];
    f32x16 acc[2];
#pragma unroll
    for (int f = 0; f < 2; f++) {
        const int jb = (wn << 1) + f;
#pragma unroll
        for (int q = 0; q < 4; q++) {
            const int j0 = (jb << 5) + (q << 3) + (hi << 2);
            float4 hv = *(const float4*)(S + (size_t)(r0 + r)*1024 + j0);
            float4 bb = *(const float4*)(Bb + j0);
            h[f][4*q+0] = hv.x; h[f][4*q+1] = hv.y;
            h[f][4*q+2] = hv.z; h[f][4*q+3] = hv.w;
            acc[f][4*q+0] = bb.x; acc[f][4*q+1] = bb.y;
            acc[f][4*q+2] = bb.z; acc[f][4*q+3] = bb.w;
        }
    }

    __syncthreads();                 // X-frags visible

    // ---- xp^T = Wx @ X^T + b (bf16) ----
    gemm2<32>(acc, XPl, Wxp, lane, wn);

    __syncthreads();                 // all waves done reading X region

    // ---- xp*256 -> XPl (bf16 frag layout, overwrites X region) ----
#pragma unroll
    for (int f = 0; f < 2; f++)
#pragma unroll
        for (int q = 0; q < 4; q++) {
            const int idx = ((((wn << 3) + (f << 2) + q) << 6) + lane) << 2;
            *(uint2*)&XPl[idx] =
                make_uint2(pk2(acc[f][4*q+0]*WSCALE, acc[f][4*q+1]*WSCALE),
                           pk2(acc[f][4*q+2]*WSCALE, acc[f][4*q+3]*WSCALE));
        }

    // ---- arg write (fp8, MX B-frag layout; identical to round 9) ----
    auto writeArg = [&](u8* wb, bool useK, float cs) {
#pragma unroll
        for (int f = 0; f < 2; f++) {
            const int jb = (wn << 1) + f;
            const int base = ((jb >> 1) << 11) + ((((jb & 1) << 5) + r) << 4) + (hi << 2);
#pragma unroll
            for (int q = 0; q < 4; q++) {
                float v0 = h[f][4*q+0], v1 = h[f][4*q+1];
                float v2 = h[f][4*q+2], v3 = h[f][4*q+3];
                if (useK) {
                    v0 += cs * acc[f][4*q+0]; v1 += cs * acc[f][4*q+1];
                    v2 += cs * acc[f][4*q+2]; v3 += cs * acc[f][4*q+3];
                }
                const int idx = base + ((q >> 1) << 10) + ((q & 1) << 3);
                *(u32*)(wb + idx) = pkfp8x4(v0, v1, v2, v3);
            }
        }
    };

    writeArg(ARGA, false, 0.0f);     // arg := h  (buffer 0)
    __syncthreads();

    float hacc[2][16];

#pragma unroll 1
    for (int u = 0; u < NUNF; u++) {
        // hacc := h (base for this unfold's weighted k-sum)
#pragma unroll
        for (int f = 0; f < 2; f++)
#pragma unroll
            for (int e = 0; e < 16; e++) hacc[f][e] = h[f][e];

#pragma unroll 1
        for (int s = 0; s < 4; s++) {
            const int   t4 = (u << 2) + s;           // global stage index
            const u8*   rb = (t4 & 1) ? ARGB : ARGA;
            u8*         wb = (t4 & 1) ? ARGA : ARGB;
            const float wk = (s == 1 || s == 2) ? (1.0f / 3.0f) : (1.0f / 6.0f);

            // acc := 256*xp (from LDS)
#pragma unroll
            for (int f = 0; f < 2; f++)
#pragma unroll
                for (int q = 0; q < 4; q++) {
                    const int idx = ((((wn << 3) + (f << 2) + q) << 6) + lane) << 2;
                    uint2 xv = *(const uint2*)&XPl[idx];
                    acc[f][4*q+0] = bf2f((u16)xv.x);
                    acc[f][4*q+1] = __uint_as_float(xv.x & 0xffff0000u);
                    acc[f][4*q+2] = bf2f((u16)xv.y);
                    acc[f][4*q+3] = __uint_as_float(xv.y & 0xffff0000u);
                }

            // acc += (256*Wh) @ arg^T   (MX fp8, both fragments, shared B)
            gemm_mx2(acc, rb, Whp8, lane, wn);

            // k = DT*tanh(acc/256) = DT - 2DT/(e^{2acc/256}+1); hacc += wk*k
#pragma unroll
            for (int f = 0; f < 2; f++)
#pragma unroll
                for (int e = 0; e < 16; e++) {
                    const float ee = __expf((2.0f / WSCALE) * acc[f][e]);
                    const float k  = fmaf(-2.0f * DT, __frcp_rn(ee + 1.0f), DT);
                    hacc[f][e] = fmaf(wk, k, hacc[f][e]);
                    acc[f][e]  = k;
                }

            if (s < 3) {
                writeArg(wb, true, (s < 2) ? 0.5f : 1.0f);  // arg := h + cs*k
                __syncthreads();     // wb ready; also releases rb for next write
            } else {
                // h := hacc (weights 1/6,1/3,1/3,1/6 already folded)
#pragma unroll
                for (int f = 0; f < 2; f++)
#pragma unroll
                    for (int e = 0; e < 16; e++) h[f][e] = hacc[f][e];
                if (u < NUNF - 1) {
                    writeArg(wb, false, 0.0f);   // arg := h (next unfold)
                    __syncthreads();
                }
            }
        }
    }

    // ---- output: float4 per (f,q) ----
#pragma unroll
    for (int f = 0; f < 2; f++) {
        const int jb = (wn << 1) + f;
#pragma unroll
        for (int q = 0; q < 4; q++) {
            const int j0 = (jb << 5) + (q << 3) + (hi << 2);
            float4 ov = make_float4(h[f][4*q+0], h[f][4*q+1],
                                    h[f][4*q+2], h[f][4*q+3]);
            *(float4*)(Out + (size_t)(r0 + r)*1024 + j0) = ov;
        }
    }
}

// ---------------------------------------------------------------------------
extern "C" void kernel_launch(void* const* d_in, const int* in_sizes, int n_in,
                              void* d_out, int out_size, void* d_ws, size_t ws_size,
                              hipStream_t stream)
{
    const float* X  = (const float*)d_in[0];   // 32768*512
    const float* S  = (const float*)d_in[1];   // 32768*1024
    const float* W  = (const float*)d_in[2];   // 1024*1536
    const float* Bb = (const float*)d_in[3];   // 1024
    float* Out = (float*)d_out;

    u16* Wxp  = (u16*)d_ws;                    // 1 MB bf16 frags (Wx)
    u8*  Whp8 = (u8*)d_ws + (1 << 20);         // 1 MB fp8 MX frags (Wh*256)

    pack_w<<<768, 256, 0, stream>>>(W, Wxp, Whp8);
    fused_rk4<<<1024, 1024, 0, stream>>>(X, S, Bb, Wxp, Whp8, Out);
}